// Round 12
// baseline (91.089 us; speedup 1.0000x reference)
//
#include <hip/hip_runtime.h>
#include <math.h>

// B=4, N=8, T=512, D=256, H=8, DK=32. BN=32, ROWS=16384.
// R12: GEMMs re-tiled to 64Mx128N / 2 waves / 128 threads / 24KB LDS ->
// 6 blocks/CU (was 3) for cross-block latency hiding. Same per-wave 64x64
// fragment math as R9-R11. Attention (q-inner) and cvtprep unchanged.

typedef __attribute__((ext_vector_type(8))) short bf16x8;
typedef __attribute__((ext_vector_type(4))) float f32x4;
typedef __attribute__((ext_vector_type(16))) float f32x16;
typedef __attribute__((ext_vector_type(4))) int i32x4;

__device__ __forceinline__ unsigned short f2bf(float f) {
    unsigned u = __float_as_uint(f);
    return (unsigned short)((u + 0x7fff + ((u >> 16) & 1)) >> 16);
}
__device__ __forceinline__ float ex2(float x) {
    float r; asm("v_exp_f32 %0, %1" : "=v"(r) : "v"(x)); return r;
}
__device__ __forceinline__ int cvtpk(float lo, float hi) {
    int r; asm("v_cvt_pk_bf16_f32 %0, %1, %2" : "=v"(r) : "v"(lo), "v"(hi)); return r;
}
__device__ __forceinline__ void gll16(const void* gsrc, const void* ldst) {
    __builtin_amdgcn_global_load_lds(
        (const __attribute__((address_space(1))) unsigned int*)gsrc,
        (__attribute__((address_space(3))) unsigned int*)ldst, 16, 0, 0);
}

// scale(1/sqrt(32)) * log2(e): folded into Q projection -> softmax in exp2 domain
#define SCL (0.17677669529663689f * 1.4426950408889634f)

// ---- workspace byte offsets ----
#define OFF_XPQ  0u           // 32*514*256 bf16 (padded)
#define OFF_XPK  8421376u
#define OFF_VB   16842752u    // 16384*256 bf16
#define OFF_BTQ  25231360u    // 256*768 bf16
#define OFF_BTK  25624576u
#define OFF_BEFF 26017792u    // 2*256 f32
#define OFF_WVT  26019840u    // 256*256 bf16
#define OFF_WOT  26150912u    // 256*256 bf16
#define OFF_QB   26413056u    // 16384*256 bf16
#define OFF_KB   34801664u
#define OFF_VV   43190272u
#define OFF_CTX  51578880u

// ---------------- fused conversion + weight prep (one launch) ----------------
__global__ __launch_bounds__(256) void cvtprep(
    const float* __restrict__ q, const float* __restrict__ k, const float* __restrict__ v,
    unsigned short* __restrict__ xpq, unsigned short* __restrict__ xpk,
    unsigned short* __restrict__ vb,
    const float* __restrict__ Wq, const float* __restrict__ Wk,
    const float* __restrict__ bq, const float* __restrict__ bk,
    const float* __restrict__ wp, const float* __restrict__ wv,
    const float* __restrict__ wa, const float* __restrict__ b_pos,
    const float* __restrict__ Wv, const float* __restrict__ Wo,
    unsigned short* __restrict__ BtQ, unsigned short* __restrict__ BtK,
    float* __restrict__ beff, unsigned short* __restrict__ WVT,
    unsigned short* __restrict__ WOT)
{
    int bid = blockIdx.x;
    if (bid < 4112) {                       // padded q/k conversion
        int idx = bid * 256 + threadIdx.x;  // 2 * 32*514*32
        int which = idx / 526336;
        int r = idx - which * 526336;
        int bn = r / 16448;
        int rr = r - bn * 16448;
        int p = rr >> 5;
        int c8 = (rr & 31) * 8;
        const float* src = which ? k : q;
        unsigned short* dst = which ? xpk : xpq;
        unsigned o[4] = {0, 0, 0, 0};
        if (p != 0 && p != 513) {
            const float* s = src + ((size_t)(bn * 512 + p - 1) * 256 + c8);
            float4 a = *(const float4*)s;
            float4 b = *(const float4*)(s + 4);
            o[0] = f2bf(a.x) | ((unsigned)f2bf(a.y) << 16);
            o[1] = f2bf(a.z) | ((unsigned)f2bf(a.w) << 16);
            o[2] = f2bf(b.x) | ((unsigned)f2bf(b.y) << 16);
            o[3] = f2bf(b.z) | ((unsigned)f2bf(b.w) << 16);
        }
        unsigned* d = (unsigned*)(dst + ((size_t)(bn * 514 + p) * 256 + c8));
        d[0] = o[0]; d[1] = o[1]; d[2] = o[2]; d[3] = o[3];
    } else if (bid < 6160) {                // v conversion
        int idx = (bid - 4112) * 256 + threadIdx.x;   // 16384*32
        int row = idx >> 5;
        int c8 = (idx & 31) * 8;
        const float* s = v + ((size_t)row * 256 + c8);
        float4 a = *(const float4*)s;
        float4 b = *(const float4*)(s + 4);
        unsigned* d = (unsigned*)(vb + ((size_t)row * 256 + c8));
        d[0] = f2bf(a.x) | ((unsigned)f2bf(a.y) << 16);
        d[1] = f2bf(a.z) | ((unsigned)f2bf(a.w) << 16);
        d[2] = f2bf(b.x) | ((unsigned)f2bf(b.y) << 16);
        d[3] = f2bf(b.z) | ((unsigned)f2bf(b.w) << 16);
    } else if (bid < 7696) {                // folded conv mats (Q side pre-scaled)
        int idx = (bid - 6160) * 256 + threadIdx.x;   // 2*3*256*256
        int which = idx / 196608;
        int r = idx - which * 196608;
        int j = r >> 16;
        int rem = r & 65535;
        int n = rem >> 8;
        int d = rem & 255;
        const float* W = which ? Wk : Wq;
        float val = wp[d * 3 + j] * W[d * 256 + n]
                  + wv[d * 3 + j] * W[(256 + d) * 256 + n]
                  + wa[d * 3 + j] * W[(512 + d) * 256 + n];
        if (!which) val *= SCL;
        (which ? BtK : BtQ)[n * 768 + j * 256 + d] = f2bf(val);
    } else if (bid < 8208) {                // Wv / Wo transposes (bf16)
        int idx = (bid - 7696) * 256 + threadIdx.x;   // 2*65536
        int which = idx >> 16;
        int r = idx & 65535;
        int n = r >> 8, kk = r & 255;
        if (!which) WVT[n * 256 + kk] = f2bf(Wv[kk * 256 + n]);
        else        WOT[n * 256 + kk] = f2bf(Wo[kk * 256 + n]);
    } else {                                // effective biases
        int which = bid - 8208;
        int n = threadIdx.x;
        const float* W = which ? Wk : Wq;
        const float* bb = which ? bk : bq;
        float s = bb[n];
        for (int d = 0; d < 256; ++d) s = fmaf(b_pos[d], W[d * 256 + n], s);
        if (!which) s *= SCL;
        beff[which * 256 + n] = s;
    }
}

// ---------------- GEMM: 64M x 128N, BK=64, 2 waves, single-buf, 2 barriers ----------------
// A bf16. IM2COL: A = padded [32][514][256], k = tap*256 + channel.
// Else: A [16384][256], col = k & 255. LDS rows = 64 shorts (8 chunks x 16B);
// phys chunk p at row r holds logical p^(r&7) via pre-swizzled global source.
// 24KB LDS -> 6 blocks/CU; 6 staggered block phases hide the vmcnt(0) drain.
template<int KTOT, bool IM2COL, typename OutT>
__device__ __forceinline__ void gemm97(
    const unsigned short* __restrict__ A, const unsigned short* __restrict__ Bt,
    const float* __restrict__ bias, OutT* __restrict__ Out,
    unsigned short* As, unsigned short* Bs)   // As: 4096, Bs: 8192 shorts
{
    const int tid = threadIdx.x;              // 128 threads, 2 waves
    const int wid = tid >> 6, l = tid & 63;
    const int l31 = l & 31, h2 = l >> 5;
    const int wn = wid;                       // wave n-strip; wm == 0
    const int m0 = blockIdx.x * 64, n0 = blockIdx.y * 128;

    f32x16 acc[2][2] = {};

    for (int k0 = 0; k0 < KTOT; k0 += 64) {
        __syncthreads();
        #pragma unroll
        for (int q = 0; q < 4; ++q) {         // A: 512 chunks
            int cidx = q * 128 + tid;
            int row = cidx >> 3;
            int csrc = ((cidx & 7) ^ (row & 7)) * 8;
            const unsigned short* asrc;
            if constexpr (IM2COL) {
                int seq = m0 >> 9, t0 = m0 & 511;
                asrc = A + ((size_t)(seq * 514 + t0 + row + (k0 >> 8)) * 256 + (k0 & 255) + csrc);
            } else {
                asrc = A + ((size_t)(m0 + row) * 256 + (k0 & 255) + csrc);
            }
            gll16(asrc, As + (q * 128 + wid * 64) * 8);
        }
        #pragma unroll
        for (int q = 0; q < 8; ++q) {         // B: 1024 chunks
            int cidx = q * 128 + tid;
            int row = cidx >> 3;
            int csrc = ((cidx & 7) ^ (row & 7)) * 8;
            gll16(Bt + (size_t)(n0 + row) * KTOT + k0 + csrc, Bs + (q * 128 + wid * 64) * 8);
        }
        __syncthreads();
        #pragma unroll
        for (int ks = 0; ks < 4; ++ks) {
            bf16x8 af[2], bfr[2];
            #pragma unroll
            for (int mt = 0; mt < 2; ++mt) {
                int r = mt * 32 + l31;
                af[mt] = *(const bf16x8*)&As[r * 64 + (((ks * 2 + h2) ^ (r & 7)) * 8)];
            }
            #pragma unroll
            for (int nt = 0; nt < 2; ++nt) {
                int rn = wn * 64 + nt * 32 + l31;
                bfr[nt] = *(const bf16x8*)&Bs[rn * 64 + (((ks * 2 + h2) ^ (rn & 7)) * 8)];
            }
            #pragma unroll
            for (int mt = 0; mt < 2; ++mt)
                #pragma unroll
                for (int nt = 0; nt < 2; ++nt)
                    acc[mt][nt] = __builtin_amdgcn_mfma_f32_32x32x16_bf16(af[mt], bfr[nt], acc[mt][nt], 0, 0, 0);
        }
    }

    // epilogue: C/D 32x32 layout: col = lane&31, row = (reg&3) + 8*(reg>>2) + 4*(lane>>5)
    #pragma unroll
    for (int nt = 0; nt < 2; ++nt) {
        const int col = n0 + wn * 64 + nt * 32 + l31;
        const float bb = bias[col];
        #pragma unroll
        for (int mt = 0; mt < 2; ++mt) {
            #pragma unroll
            for (int r = 0; r < 16; ++r) {
                const int row = m0 + mt * 32 + 4 * h2 + (r & 3) + 8 * (r >> 2);
                float v = acc[mt][nt][r] + bb;
                if constexpr (sizeof(OutT) == 2) Out[(size_t)row * 256 + col] = (OutT)f2bf(v);
                else Out[(size_t)row * 256 + col] = v;
            }
        }
    }
}

__global__ __launch_bounds__(128) void proj_fused(
    const unsigned short* __restrict__ XPQ, const unsigned short* __restrict__ XPK,
    const unsigned short* __restrict__ VB,
    const unsigned short* __restrict__ BTQ, const unsigned short* __restrict__ BTK,
    const unsigned short* __restrict__ WVT,
    const float* __restrict__ BEFF, const float* __restrict__ bv,
    unsigned short* __restrict__ QB, unsigned short* __restrict__ KB,
    unsigned short* __restrict__ VV)
{
    __shared__ alignas(16) unsigned short As[4096];
    __shared__ alignas(16) unsigned short Bs[8192];
    const int z = blockIdx.z;
    if (z == 0)      gemm97<768, true, unsigned short>(XPQ, BTQ, BEFF, QB, As, Bs);
    else if (z == 1) gemm97<768, true, unsigned short>(XPK, BTK, BEFF + 256, KB, As, Bs);
    else             gemm97<256, false, unsigned short>(VB, WVT, bv, VV, As, Bs);
}

__global__ __launch_bounds__(128) void outproj(
    const unsigned short* __restrict__ CTX, const unsigned short* __restrict__ WOT,
    const float* __restrict__ bo, float* __restrict__ Out)
{
    __shared__ alignas(16) unsigned short As[4096];
    __shared__ alignas(16) unsigned short Bs[8192];
    gemm97<256, false, float>(CTX, WOT, bo, Out, As, Bs);
}

// ---------------- q-inner fused attention: 1 block per (bn,h), 8 waves ----------------
__global__ __launch_bounds__(512) void attn_mfma(const unsigned short* __restrict__ Qb,
                                                 const unsigned short* __restrict__ Kb,
                                                 const unsigned short* __restrict__ Vv,
                                                 const int* __restrict__ mask,
                                                 unsigned short* __restrict__ ctx) {
    __shared__ alignas(16) unsigned short Qs[512 * 32];      // full Q head-slice
    __shared__ alignas(16) unsigned short Ks[2][128 * 32];   // chunk-xor (c ^ (row&3))
    __shared__ alignas(16) unsigned short VsT[2][32 * 136];  // [d][key], 17-chunk rows
    __shared__ float Mb[2][128];

    const int bnh = blockIdx.x;
    const int bn = bnh >> 3, h = bnh & 7;
    const int tid = threadIdx.x, wid = tid >> 6, l = tid & 63;
    const int g = l >> 4, r15 = l & 15;
    const unsigned short* Qg = Qb + (size_t)bn * 512 * 256 + h * 32;
    const unsigned short* Kg = Kb + (size_t)bn * 512 * 256 + h * 32;
    const unsigned short* Vg = Vv + (size_t)bn * 512 * 256 + h * 32;
    const int* mp = mask + bn * 512;
    const int srow = tid >> 2;                       // K staging row (512 thr, 1 chunk each)
    const int vkey = tid & 127, vd0 = (tid >> 7) * 8;

    auto stageK = [&](int k0, int b) {
        int csrc = (((tid & 3) ^ (srow & 3))) * 8;
        gll16(Kg + ((size_t)(k0 + srow)) * 256 + csrc, &Ks[b][wid * 512]);
    };

    // ---- prologue: full Q, K0, V0, Mb0 ----
    #pragma unroll
    for (int q = 0; q < 4; ++q) {
        int chunk = q * 512 + tid;
        int row = chunk >> 2, c = chunk & 3;
        gll16(Qg + (size_t)row * 256 + c * 8, Qs + (q * 512 + wid * 64) * 8);
    }
    stageK(0, 0);
    {
        i32x4 vr = *(const i32x4*)(const void*)(Vg + (size_t)vkey * 256 + vd0);
        #pragma unroll
        for (int i = 0; i < 4; ++i) {
            unsigned u = (unsigned)vr[i];
            VsT[0][(vd0 + 2 * i) * 136 + vkey] = (unsigned short)(u & 0xffff);
            VsT[0][(vd0 + 2 * i + 1) * 136 + vkey] = (unsigned short)(u >> 16);
        }
        if (tid < 128) Mb[0][tid] = (mp[tid] != 0) ? -1e9f : 0.f;
    }
    __syncthreads();

    // Q fragments for all 4 q-tiles (each wave owns strip wid of each tile)
    bf16x8 bq[4];
    #pragma unroll
    for (int qt = 0; qt < 4; ++qt)
        bq[qt] = *(const bf16x8*)&Qs[(qt * 128 + wid * 16 + r15) * 32 + g * 8];

    float mrun[4], lrun[4];
    f32x4 accO[4][2] = {};
    #pragma unroll
    for (int qt = 0; qt < 4; ++qt) { mrun[qt] = -1e30f; lrun[qt] = 0.f; }

    for (int kt = 0; kt < 4; ++kt) {
        const int cur = kt & 1, nxt = cur ^ 1;
        const int k0n = kt * 128 + 128;

        // ---- issue next-tile loads early ----
        i32x4 vr;
        int mraw = 0;
        if (kt < 3) {
            stageK(k0n, nxt);
            vr = *(const i32x4*)(const void*)(Vg + ((size_t)(k0n + vkey)) * 256 + vd0);
            if (tid < 128) mraw = mp[k0n + tid];
        }

        // hoist V fragments for this kt (reused by all 4 q-tiles)
        bf16x8 av[2][4];
        #pragma unroll
        for (int mt = 0; mt < 2; ++mt)
            #pragma unroll
            for (int s = 0; s < 4; ++s)
                av[mt][s] = *(const bf16x8*)&VsT[cur][(mt * 16 + r15) * 136 + 32 * s + 8 * g];

        #pragma unroll
        for (int qt = 0; qt < 4; ++qt) {
            // ---- QK^T (swapped, permuted A rows), mask bias as MFMA C-in ----
            float p[8][4];
            float rmax = -3e38f;
            __builtin_amdgcn_s_setprio(1);
            #pragma unroll
            for (int t2 = 0; t2 < 8; ++t2) {
                const int base = 32 * (t2 >> 1) + 4 * (t2 & 1);
                const int arow = base + 8 * (r15 >> 2) + (r15 & 3);
                bf16x8 ak = *(const bf16x8*)&Ks[cur][arow * 32 + ((g ^ (arow & 3)) * 8)];
                f32x4 cin = *(const f32x4*)&Mb[cur][base + 8 * g];
                f32x4 st = __builtin_amdgcn_mfma_f32_16x16x32_bf16(ak, bq[qt], cin, 0, 0, 0);
                #pragma unroll
                for (int r = 0; r < 4; ++r) p[t2][r] = st[r];
                rmax = fmaxf(rmax, fmaxf(fmaxf(st[0], st[1]), fmaxf(st[2], st[3])));
            }
            __builtin_amdgcn_s_setprio(0);
            rmax = fmaxf(rmax, __shfl_xor(rmax, 16, 64));
            rmax = fmaxf(rmax, __shfl_xor(rmax, 32, 64));

            if (__ballot(rmax > mrun[qt])) {
                float mnew = fmaxf(mrun[qt], rmax);
                float fs = ex2(mrun[qt] - mnew);
                lrun[qt] *= fs;
                accO[qt][0] *= fs;
                accO[qt][1] *= fs;
                mrun[qt] = mnew;
            }
            float psum = 0.f;
            #pragma unroll
            for (int t2 = 0; t2 < 8; ++t2)
                #pragma unroll
                for (int r = 0; r < 4; ++r) {
                    float e = ex2(p[t2][r] - mrun[qt]);
                    p[t2][r] = e;
                    psum += e;
                }
            psum += __shfl_xor(psum, 16, 64);
            psum += __shfl_xor(psum, 32, 64);
            lrun[qt] += psum;

            // ---- pack P (lane holds exactly its PV B-frag keys) ----
            bf16x8 pb[4];
            #pragma unroll
            for (int s = 0; s < 4; ++s) {
                i32x4 bi = {cvtpk(p[2 * s][0], p[2 * s][1]), cvtpk(p[2 * s][2], p[2 * s][3]),
                            cvtpk(p[2 * s + 1][0], p[2 * s + 1][1]), cvtpk(p[2 * s + 1][2], p[2 * s + 1][3])};
                pb[s] = __builtin_bit_cast(bf16x8, bi);
            }

            // ---- PV: accO (O^T tile) += V^T x P^T ----
            __builtin_amdgcn_s_setprio(1);
            #pragma unroll
            for (int mt = 0; mt < 2; ++mt)
                #pragma unroll
                for (int s = 0; s < 4; ++s)
                    accO[qt][mt] = __builtin_amdgcn_mfma_f32_16x16x32_bf16(av[mt][s], pb[s], accO[qt][mt], 0, 0, 0);
            __builtin_amdgcn_s_setprio(0);
        }

        // ---- write-late: V(kt+1) regs -> LDS, mask bias ----
        if (kt < 3) {
            #pragma unroll
            for (int i = 0; i < 4; ++i) {
                unsigned u = (unsigned)vr[i];
                VsT[nxt][(vd0 + 2 * i) * 136 + vkey] = (unsigned short)(u & 0xffff);
                VsT[nxt][(vd0 + 2 * i + 1) * 136 + vkey] = (unsigned short)(u >> 16);
            }
            if (tid < 128) Mb[nxt][tid] = (mraw != 0) ? -1e9f : 0.f;
        }
        __syncthreads();
    }

    #pragma unroll
    for (int qt = 0; qt < 4; ++qt) {
        const float inv = 1.f / lrun[qt];
        const size_t orow = (size_t)bn * 512 + qt * 128 + wid * 16 + r15;
        #pragma unroll
        for (int mt = 0; mt < 2; ++mt) {
            ushort4 o;
            o.x = f2bf(accO[qt][mt][0] * inv);
            o.y = f2bf(accO[qt][mt][1] * inv);
            o.z = f2bf(accO[qt][mt][2] * inv);
            o.w = f2bf(accO[qt][mt][3] * inv);
            *(ushort4*)&ctx[orow * 256 + h * 32 + mt * 16 + 4 * g] = o;
        }
    }
}

extern "C" void kernel_launch(void* const* d_in, const int* in_sizes, int n_in,
                              void* d_out, int out_size, void* d_ws, size_t ws_size,
                              hipStream_t stream) {
    const float* query = (const float*)d_in[0];
    const float* key   = (const float*)d_in[1];
    const float* value = (const float*)d_in[2];
    const int*   kpm   = (const int*)d_in[3];
    const float* w_pos = (const float*)d_in[4];
    const float* b_pos = (const float*)d_in[5];
    const float* w_vel = (const float*)d_in[6];
    const float* w_acc = (const float*)d_in[7];
    const float* Wq    = (const float*)d_in[8];
    const float* bq    = (const float*)d_in[9];
    const float* Wk    = (const float*)d_in[10];
    const float* bk    = (const float*)d_in[11];
    const float* Wv    = (const float*)d_in[12];
    const float* bv    = (const float*)d_in[13];
    const float* Wo    = (const float*)d_in[14];
    const float* bo    = (const float*)d_in[15];

    unsigned char* w = (unsigned char*)d_ws;
    unsigned short* XPQ = (unsigned short*)(w + OFF_XPQ);
    unsigned short* XPK = (unsigned short*)(w + OFF_XPK);
    unsigned short* VB  = (unsigned short*)(w + OFF_VB);
    unsigned short* BTQ = (unsigned short*)(w + OFF_BTQ);
    unsigned short* BTK = (unsigned short*)(w + OFF_BTK);
    float*          BEFF= (float*)(w + OFF_BEFF);
    unsigned short* WVT = (unsigned short*)(w + OFF_WVT);
    unsigned short* WOT = (unsigned short*)(w + OFF_WOT);
    unsigned short* QB  = (unsigned short*)(w + OFF_QB);
    unsigned short* KB  = (unsigned short*)(w + OFF_KB);
    unsigned short* VV  = (unsigned short*)(w + OFF_VV);
    unsigned short* CTX = (unsigned short*)(w + OFF_CTX);

    cvtprep<<<8210, 256, 0, stream>>>(query, key, value, XPQ, XPK, VB,
                                      Wq, Wk, bq, bk, w_pos, w_vel, w_acc, b_pos,
                                      Wv, Wo, BTQ, BTK, BEFF, WVT, WOT);

    proj_fused<<<dim3(256, 2, 3), 128, 0, stream>>>(XPQ, XPK, VB, BTQ, BTK, WVT,
                                                    BEFF, bv, QB, KB, VV);

    attn_mfma<<<256, 512, 0, stream>>>(QB, KB, VV, kpm, CTX);

    outproj<<<dim3(256, 2), 128, 0, stream>>>(CTX, WOT, bo, (float*)d_out);
}

// Round 13
// 80.771 us; speedup vs baseline: 1.1277x; 1.1277x over previous
//
#include <hip/hip_runtime.h>
#include <math.h>

// B=4, N=8, T=512, D=256, H=8, DK=32. BN=32, ROWS=16384.
// R13: GEMM reverted to R11 geometry (128x128, 4 waves, single-buf, 2 barriers).
// Q/K/V projections read fp32 inputs DIRECTLY via global_load_lds (fp32 A tile
// in LDS, cvt_pk at fragment-load time) -> XP/VB materialization pass deleted.
// Weight prep only (~1.5us). attn (q-inner) and outproj unchanged from R11.

typedef __attribute__((ext_vector_type(8))) short bf16x8;
typedef __attribute__((ext_vector_type(4))) float f32x4;
typedef __attribute__((ext_vector_type(16))) float f32x16;
typedef __attribute__((ext_vector_type(4))) int i32x4;

__device__ __forceinline__ unsigned short f2bf(float f) {
    unsigned u = __float_as_uint(f);
    return (unsigned short)((u + 0x7fff + ((u >> 16) & 1)) >> 16);
}
__device__ __forceinline__ float bf2f(unsigned short h) {
    return __uint_as_float(((unsigned)h) << 16);
}
__device__ __forceinline__ float ex2(float x) {
    float r; asm("v_exp_f32 %0, %1" : "=v"(r) : "v"(x)); return r;
}
__device__ __forceinline__ int cvtpk(float lo, float hi) {
    int r; asm("v_cvt_pk_bf16_f32 %0, %1, %2" : "=v"(r) : "v"(lo), "v"(hi)); return r;
}
__device__ __forceinline__ void gll16(const void* gsrc, const void* ldst) {
    __builtin_amdgcn_global_load_lds(
        (const __attribute__((address_space(1))) unsigned int*)gsrc,
        (__attribute__((address_space(3))) unsigned int*)ldst, 16, 0, 0);
}

// scale(1/sqrt(32)) * log2(e): folded into Q projection -> softmax in exp2 domain
#define SCL (0.17677669529663689f * 1.4426950408889634f)

// ---- workspace byte offsets ----
#define OFF_ZERO 0u           // 64 f32 zero-page for im2col edge rows
#define OFF_BTQ  25231360u    // 256*768 bf16
#define OFF_BTK  25624576u
#define OFF_BEFF 26017792u    // 2*256 f32
#define OFF_WVT  26019840u    // 256*256 bf16
#define OFF_WOT  26150912u    // 256*256 bf16
#define OFF_QB   26413056u    // 16384*256 bf16
#define OFF_KB   34801664u
#define OFF_VV   43190272u
#define OFF_CTX  51578880u

// ---------------- weight prep (folded conv mats, transposes, biases, zero-page) ----------------
__global__ __launch_bounds__(256) void prep(
    const float* __restrict__ Wq, const float* __restrict__ Wk,
    const float* __restrict__ bq, const float* __restrict__ bk,
    const float* __restrict__ wp, const float* __restrict__ wv,
    const float* __restrict__ wa, const float* __restrict__ b_pos,
    const float* __restrict__ Wv, const float* __restrict__ Wo,
    unsigned short* __restrict__ BtQ, unsigned short* __restrict__ BtK,
    float* __restrict__ beff, unsigned short* __restrict__ WVT,
    unsigned short* __restrict__ WOT, float* __restrict__ zeropage)
{
    int bid = blockIdx.x;
    if (bid < 1536) {                       // folded conv mats (Q side pre-scaled)
        int idx = bid * 256 + threadIdx.x;  // 2*3*256*256
        int which = idx / 196608;
        int r = idx - which * 196608;
        int j = r >> 16;
        int rem = r & 65535;
        int n = rem >> 8;
        int d = rem & 255;
        const float* W = which ? Wk : Wq;
        float val = wp[d * 3 + j] * W[d * 256 + n]
                  + wv[d * 3 + j] * W[(256 + d) * 256 + n]
                  + wa[d * 3 + j] * W[(512 + d) * 256 + n];
        if (!which) val *= SCL;
        (which ? BtK : BtQ)[n * 768 + j * 256 + d] = f2bf(val);
    } else if (bid < 2048) {                // Wv / Wo transposes (bf16)
        int idx = (bid - 1536) * 256 + threadIdx.x;   // 2*65536
        int which = idx >> 16;
        int r = idx & 65535;
        int n = r >> 8, kk = r & 255;
        if (!which) WVT[n * 256 + kk] = f2bf(Wv[kk * 256 + n]);
        else        WOT[n * 256 + kk] = f2bf(Wo[kk * 256 + n]);
    } else if (bid < 2050) {                // effective biases
        int which = bid - 2048;
        int n = threadIdx.x;
        const float* W = which ? Wk : Wq;
        const float* bb = which ? bk : bq;
        float s = bb[n];
        for (int d = 0; d < 256; ++d) s = fmaf(b_pos[d], W[d * 256 + n], s);
        if (!which) s *= SCL;
        beff[which * 256 + n] = s;
    } else {                                // zero-page (64 floats)
        if (threadIdx.x < 64) zeropage[threadIdx.x] = 0.f;
    }
}

// ---------------- fp32-A GEMM: 128M x 128N, BK=64, single-buf, 2 barriers ----------------
// A fp32 read directly (IM2COL: k = tap*256 + channel, edge rows -> zero-page).
// B bf16 [256 n][KTOT k]. A LDS rows = 64 f32 (16 chunks x 16B), phys chunk p
// at row r holds logical p^(r&15) via pre-swizzled source; B rows = 64 bf16
// (8 chunks), phys p^(r&7). bf16 conversion at fragment time via v_cvt_pk
// (RNE, bitwise-identical to pre-converted path).
template<int KTOT, bool IM2COL>
__device__ __forceinline__ void gemmf32(
    const float* __restrict__ A, const unsigned short* __restrict__ Bt,
    const float* __restrict__ bias, const float* __restrict__ zeropage,
    unsigned short* __restrict__ Out, float* Asf, unsigned short* Bs)
{
    const int tid = threadIdx.x;
    const int wid = tid >> 6, l = tid & 63;
    const int l31 = l & 31, h2 = l >> 5;
    const int wm = wid >> 1, wn = wid & 1;
    const int m0 = blockIdx.x * 128, n0 = blockIdx.y * 128;

    f32x16 acc[2][2] = {};

    for (int k0 = 0; k0 < KTOT; k0 += 64) {
        __syncthreads();
        // ---- stage A fp32: 2048 chunks (8 per thread) ----
        #pragma unroll
        for (int q = 0; q < 8; ++q) {
            int cidx = q * 256 + tid;
            int row = cidx >> 4, cch = cidx & 15;
            int csrc = (cch ^ (row & 15)) * 4;          // float offset in 64-wide slice
            const float* asrc;
            if constexpr (IM2COL) {
                int seq = m0 >> 9, t0 = m0 & 511;
                int st = t0 + row + (k0 >> 8) - 1;
                asrc = (st >= 0 && st < 512)
                     ? A + ((size_t)(seq * 512 + st) * 256 + (k0 & 255) + csrc)
                     : zeropage + csrc;
            } else {
                asrc = A + ((size_t)(m0 + row) * 256 + k0 + csrc);
            }
            gll16(asrc, Asf + (size_t)cidx * 4);
        }
        // ---- stage B bf16: 1024 chunks (4 per thread) ----
        #pragma unroll
        for (int q = 0; q < 4; ++q) {
            int cidx = q * 256 + tid;
            int row = cidx >> 3, c = cidx & 7;
            gll16(Bt + (size_t)(n0 + row) * KTOT + k0 + ((c ^ (row & 7)) * 8),
                  Bs + cidx * 8);
        }
        __syncthreads();
        #pragma unroll
        for (int ks = 0; ks < 4; ++ks) {
            const int c = ks * 2 + h2;                  // logical 8-elem chunk 0..7
            bf16x8 af[2], bfr[2];
            #pragma unroll
            for (int mt = 0; mt < 2; ++mt) {
                int r = wm * 64 + mt * 32 + l31;
                f32x4 f0 = *(const f32x4*)&Asf[r * 64 + (((2 * c) ^ (r & 15)) * 4)];
                f32x4 f1 = *(const f32x4*)&Asf[r * 64 + (((2 * c + 1) ^ (r & 15)) * 4)];
                i32x4 w = {cvtpk(f0[0], f0[1]), cvtpk(f0[2], f0[3]),
                           cvtpk(f1[0], f1[1]), cvtpk(f1[2], f1[3])};
                af[mt] = __builtin_bit_cast(bf16x8, w);
            }
            #pragma unroll
            for (int nt = 0; nt < 2; ++nt) {
                int rn = wn * 64 + nt * 32 + l31;
                bfr[nt] = *(const bf16x8*)&Bs[rn * 64 + ((c ^ (rn & 7)) * 8)];
            }
            #pragma unroll
            for (int mt = 0; mt < 2; ++mt)
                #pragma unroll
                for (int nt = 0; nt < 2; ++nt)
                    acc[mt][nt] = __builtin_amdgcn_mfma_f32_32x32x16_bf16(af[mt], bfr[nt], acc[mt][nt], 0, 0, 0);
        }
    }

    // epilogue: C/D 32x32 layout: col = lane&31, row = (reg&3) + 8*(reg>>2) + 4*(lane>>5)
    #pragma unroll
    for (int nt = 0; nt < 2; ++nt) {
        const int col = n0 + wn * 64 + nt * 32 + l31;
        const float bb = bias[col];
        #pragma unroll
        for (int mt = 0; mt < 2; ++mt) {
            #pragma unroll
            for (int r = 0; r < 16; ++r) {
                const int row = m0 + wm * 64 + mt * 32 + 4 * h2 + (r & 3) + 8 * (r >> 2);
                Out[(size_t)row * 256 + col] = f2bf(acc[mt][nt][r] + bb);
            }
        }
    }
}

// ---------------- bf16-A GEMM (outproj): 128M x 128N, BK=64 (R11 verbatim) ----------------
template<int KTOT, typename OutT>
__device__ __forceinline__ void gemm97(
    const unsigned short* __restrict__ A, const unsigned short* __restrict__ Bt,
    const float* __restrict__ bias, OutT* __restrict__ Out,
    unsigned short* As, unsigned short* Bs)
{
    const int tid = threadIdx.x;
    const int wid = tid >> 6, l = tid & 63;
    const int l31 = l & 31, h2 = l >> 5;
    const int wm = wid >> 1, wn = wid & 1;
    const int m0 = blockIdx.x * 128, n0 = blockIdx.y * 128;

    f32x16 acc[2][2] = {};

    for (int k0 = 0; k0 < KTOT; k0 += 64) {
        __syncthreads();
        #pragma unroll
        for (int q = 0; q < 4; ++q) {
            int cidx = q * 256 + tid;
            int row = cidx >> 3;
            int csrc = ((cidx & 7) ^ (row & 7)) * 8;
            gll16(A + (size_t)(m0 + row) * 256 + (k0 & 255) + csrc, As + (size_t)cidx * 8);
            gll16(Bt + (size_t)(n0 + row) * KTOT + k0 + csrc, Bs + (size_t)cidx * 8);
        }
        __syncthreads();
        #pragma unroll
        for (int ks = 0; ks < 4; ++ks) {
            bf16x8 af[2], bfr[2];
            #pragma unroll
            for (int mt = 0; mt < 2; ++mt) {
                int r = wm * 64 + mt * 32 + l31;
                af[mt] = *(const bf16x8*)&As[r * 64 + (((ks * 2 + h2) ^ (r & 7)) * 8)];
            }
            #pragma unroll
            for (int nt = 0; nt < 2; ++nt) {
                int rn = wn * 64 + nt * 32 + l31;
                bfr[nt] = *(const bf16x8*)&Bs[rn * 64 + (((ks * 2 + h2) ^ (rn & 7)) * 8)];
            }
            #pragma unroll
            for (int mt = 0; mt < 2; ++mt)
                #pragma unroll
                for (int nt = 0; nt < 2; ++nt)
                    acc[mt][nt] = __builtin_amdgcn_mfma_f32_32x32x16_bf16(af[mt], bfr[nt], acc[mt][nt], 0, 0, 0);
        }
    }

    #pragma unroll
    for (int nt = 0; nt < 2; ++nt) {
        const int col = n0 + wn * 64 + nt * 32 + l31;
        const float bb = bias[col];
        #pragma unroll
        for (int mt = 0; mt < 2; ++mt) {
            #pragma unroll
            for (int r = 0; r < 16; ++r) {
                const int row = m0 + wm * 64 + mt * 32 + 4 * h2 + (r & 3) + 8 * (r >> 2);
                float v = acc[mt][nt][r] + bb;
                if constexpr (sizeof(OutT) == 2) Out[(size_t)row * 256 + col] = (OutT)f2bf(v);
                else Out[(size_t)row * 256 + col] = v;
            }
        }
    }
}

// one launch: z=0 Q-proj, z=1 K-proj (fp32 im2col), z=2 V-proj (fp32 plain)
__global__ __launch_bounds__(256) void proj_fused(
    const float* __restrict__ query, const float* __restrict__ key,
    const float* __restrict__ value,
    const unsigned short* __restrict__ BTQ, const unsigned short* __restrict__ BTK,
    const unsigned short* __restrict__ WVT,
    const float* __restrict__ BEFF, const float* __restrict__ bv,
    const float* __restrict__ zeropage,
    unsigned short* __restrict__ QB, unsigned short* __restrict__ KB,
    unsigned short* __restrict__ VV)
{
    __shared__ alignas(16) float Asf[8192];             // 32 KB
    __shared__ alignas(16) unsigned short Bs[8192];     // 16 KB
    const int z = blockIdx.z;
    if (z == 0)      gemmf32<768, true>(query, BTQ, BEFF, zeropage, QB, Asf, Bs);
    else if (z == 1) gemmf32<768, true>(key, BTK, BEFF + 256, zeropage, KB, Asf, Bs);
    else             gemmf32<256, false>(value, WVT, bv, zeropage, VV, Asf, Bs);
}

__global__ __launch_bounds__(256) void outproj(
    const unsigned short* __restrict__ CTX, const unsigned short* __restrict__ WOT,
    const float* __restrict__ bo, float* __restrict__ Out)
{
    __shared__ alignas(16) unsigned short As[8192];
    __shared__ alignas(16) unsigned short Bs[8192];
    gemm97<256, float>(CTX, WOT, bo, Out, As, Bs);
}

// ---------------- q-inner fused attention: 1 block per (bn,h), 8 waves (R11 verbatim) ----------------
__global__ __launch_bounds__(512) void attn_mfma(const unsigned short* __restrict__ Qb,
                                                 const unsigned short* __restrict__ Kb,
                                                 const unsigned short* __restrict__ Vv,
                                                 const int* __restrict__ mask,
                                                 unsigned short* __restrict__ ctx) {
    __shared__ alignas(16) unsigned short Qs[512 * 32];      // full Q head-slice
    __shared__ alignas(16) unsigned short Ks[2][128 * 32];   // chunk-xor (c ^ (row&3))
    __shared__ alignas(16) unsigned short VsT[2][32 * 136];  // [d][key], 17-chunk rows
    __shared__ float Mb[2][128];

    const int bnh = blockIdx.x;
    const int bn = bnh >> 3, h = bnh & 7;
    const int tid = threadIdx.x, wid = tid >> 6, l = tid & 63;
    const int g = l >> 4, r15 = l & 15;
    const unsigned short* Qg = Qb + (size_t)bn * 512 * 256 + h * 32;
    const unsigned short* Kg = Kb + (size_t)bn * 512 * 256 + h * 32;
    const unsigned short* Vg = Vv + (size_t)bn * 512 * 256 + h * 32;
    const int* mp = mask + bn * 512;
    const int srow = tid >> 2;                       // K staging row
    const int vkey = tid & 127, vd0 = (tid >> 7) * 8;

    auto stageK = [&](int k0, int b) {
        int csrc = (((tid & 3) ^ (srow & 3))) * 8;
        gll16(Kg + ((size_t)(k0 + srow)) * 256 + csrc, &Ks[b][wid * 512]);
    };

    // ---- prologue: full Q, K0, V0, Mb0 ----
    #pragma unroll
    for (int q = 0; q < 4; ++q) {
        int chunk = q * 512 + tid;
        int row = chunk >> 2, c = chunk & 3;
        gll16(Qg + (size_t)row * 256 + c * 8, Qs + (q * 512 + wid * 64) * 8);
    }
    stageK(0, 0);
    {
        i32x4 vr = *(const i32x4*)(const void*)(Vg + (size_t)vkey * 256 + vd0);
        #pragma unroll
        for (int i = 0; i < 4; ++i) {
            unsigned u = (unsigned)vr[i];
            VsT[0][(vd0 + 2 * i) * 136 + vkey] = (unsigned short)(u & 0xffff);
            VsT[0][(vd0 + 2 * i + 1) * 136 + vkey] = (unsigned short)(u >> 16);
        }
        if (tid < 128) Mb[0][tid] = (mp[tid] != 0) ? -1e9f : 0.f;
    }
    __syncthreads();

    bf16x8 bq[4];
    #pragma unroll
    for (int qt = 0; qt < 4; ++qt)
        bq[qt] = *(const bf16x8*)&Qs[(qt * 128 + wid * 16 + r15) * 32 + g * 8];

    float mrun[4], lrun[4];
    f32x4 accO[4][2] = {};
    #pragma unroll
    for (int qt = 0; qt < 4; ++qt) { mrun[qt] = -1e30f; lrun[qt] = 0.f; }

    for (int kt = 0; kt < 4; ++kt) {
        const int cur = kt & 1, nxt = cur ^ 1;
        const int k0n = kt * 128 + 128;

        i32x4 vr;
        int mraw = 0;
        if (kt < 3) {
            stageK(k0n, nxt);
            vr = *(const i32x4*)(const void*)(Vg + ((size_t)(k0n + vkey)) * 256 + vd0);
            if (tid < 128) mraw = mp[k0n + tid];
        }

        bf16x8 av[2][4];
        #pragma unroll
        for (int mt = 0; mt < 2; ++mt)
            #pragma unroll
            for (int s = 0; s < 4; ++s)
                av[mt][s] = *(const bf16x8*)&VsT[cur][(mt * 16 + r15) * 136 + 32 * s + 8 * g];

        #pragma unroll
        for (int qt = 0; qt < 4; ++qt) {
            float p[8][4];
            float rmax = -3e38f;
            __builtin_amdgcn_s_setprio(1);
            #pragma unroll
            for (int t2 = 0; t2 < 8; ++t2) {
                const int base = 32 * (t2 >> 1) + 4 * (t2 & 1);
                const int arow = base + 8 * (r15 >> 2) + (r15 & 3);
                bf16x8 ak = *(const bf16x8*)&Ks[cur][arow * 32 + ((g ^ (arow & 3)) * 8)];
                f32x4 cin = *(const f32x4*)&Mb[cur][base + 8 * g];
                f32x4 st = __builtin_amdgcn_mfma_f32_16x16x32_bf16(ak, bq[qt], cin, 0, 0, 0);
                #pragma unroll
                for (int r = 0; r < 4; ++r) p[t2][r] = st[r];
                rmax = fmaxf(rmax, fmaxf(fmaxf(st[0], st[1]), fmaxf(st[2], st[3])));
            }
            __builtin_amdgcn_s_setprio(0);
            rmax = fmaxf(rmax, __shfl_xor(rmax, 16, 64));
            rmax = fmaxf(rmax, __shfl_xor(rmax, 32, 64));

            if (__ballot(rmax > mrun[qt])) {
                float mnew = fmaxf(mrun[qt], rmax);
                float fs = ex2(mrun[qt] - mnew);
                lrun[qt] *= fs;
                accO[qt][0] *= fs;
                accO[qt][1] *= fs;
                mrun[qt] = mnew;
            }
            float psum = 0.f;
            #pragma unroll
            for (int t2 = 0; t2 < 8; ++t2)
                #pragma unroll
                for (int r = 0; r < 4; ++r) {
                    float e = ex2(p[t2][r] - mrun[qt]);
                    p[t2][r] = e;
                    psum += e;
                }
            psum += __shfl_xor(psum, 16, 64);
            psum += __shfl_xor(psum, 32, 64);
            lrun[qt] += psum;

            bf16x8 pb[4];
            #pragma unroll
            for (int s = 0; s < 4; ++s) {
                i32x4 bi = {cvtpk(p[2 * s][0], p[2 * s][1]), cvtpk(p[2 * s][2], p[2 * s][3]),
                            cvtpk(p[2 * s + 1][0], p[2 * s + 1][1]), cvtpk(p[2 * s + 1][2], p[2 * s + 1][3])};
                pb[s] = __builtin_bit_cast(bf16x8, bi);
            }

            __builtin_amdgcn_s_setprio(1);
            #pragma unroll
            for (int mt = 0; mt < 2; ++mt)
                #pragma unroll
                for (int s = 0; s < 4; ++s)
                    accO[qt][mt] = __builtin_amdgcn_mfma_f32_16x16x32_bf16(av[mt][s], pb[s], accO[qt][mt], 0, 0, 0);
            __builtin_amdgcn_s_setprio(0);
        }

        if (kt < 3) {
            #pragma unroll
            for (int i = 0; i < 4; ++i) {
                unsigned u = (unsigned)vr[i];
                VsT[nxt][(vd0 + 2 * i) * 136 + vkey] = (unsigned short)(u & 0xffff);
                VsT[nxt][(vd0 + 2 * i + 1) * 136 + vkey] = (unsigned short)(u >> 16);
            }
            if (tid < 128) Mb[nxt][tid] = (mraw != 0) ? -1e9f : 0.f;
        }
        __syncthreads();
    }

    #pragma unroll
    for (int qt = 0; qt < 4; ++qt) {
        const float inv = 1.f / lrun[qt];
        const size_t orow = (size_t)bn * 512 + qt * 128 + wid * 16 + r15;
        #pragma unroll
        for (int mt = 0; mt < 2; ++mt) {
            ushort4 o;
            o.x = f2bf(accO[qt][mt][0] * inv);
            o.y = f2bf(accO[qt][mt][1] * inv);
            o.z = f2bf(accO[qt][mt][2] * inv);
            o.w = f2bf(accO[qt][mt][3] * inv);
            *(ushort4*)&ctx[orow * 256 + h * 32 + mt * 16 + 4 * g] = o;
        }
    }
}

extern "C" void kernel_launch(void* const* d_in, const int* in_sizes, int n_in,
                              void* d_out, int out_size, void* d_ws, size_t ws_size,
                              hipStream_t stream) {
    const float* query = (const float*)d_in[0];
    const float* key   = (const float*)d_in[1];
    const float* value = (const float*)d_in[2];
    const int*   kpm   = (const int*)d_in[3];
    const float* w_pos = (const float*)d_in[4];
    const float* b_pos = (const float*)d_in[5];
    const float* w_vel = (const float*)d_in[6];
    const float* w_acc = (const float*)d_in[7];
    const float* Wq    = (const float*)d_in[8];
    const float* bq    = (const float*)d_in[9];
    const float* Wk    = (const float*)d_in[10];
    const float* bk    = (const float*)d_in[11];
    const float* Wv    = (const float*)d_in[12];
    const float* bv    = (const float*)d_in[13];
    const float* Wo    = (const float*)d_in[14];
    const float* bo    = (const float*)d_in[15];

    unsigned char* w = (unsigned char*)d_ws;
    float*          ZP  = (float*)(w + OFF_ZERO);
    unsigned short* BTQ = (unsigned short*)(w + OFF_BTQ);
    unsigned short* BTK = (unsigned short*)(w + OFF_BTK);
    float*          BEFF= (float*)(w + OFF_BEFF);
    unsigned short* WVT = (unsigned short*)(w + OFF_WVT);
    unsigned short* WOT = (unsigned short*)(w + OFF_WOT);
    unsigned short* QB  = (unsigned short*)(w + OFF_QB);
    unsigned short* KB  = (unsigned short*)(w + OFF_KB);
    unsigned short* VV  = (unsigned short*)(w + OFF_VV);
    unsigned short* CTX = (unsigned short*)(w + OFF_CTX);

    prep<<<2051, 256, 0, stream>>>(Wq, Wk, bq, bk, w_pos, w_vel, w_acc, b_pos,
                                   Wv, Wo, BTQ, BTK, BEFF, WVT, WOT, ZP);

    proj_fused<<<dim3(128, 2, 3), 256, 0, stream>>>(query, key, value, BTQ, BTK, WVT,
                                                    BEFF, bv, ZP, QB, KB, VV);

    attn_mfma<<<256, 512, 0, stream>>>(QB, KB, VV, kpm, CTX);

    outproj<<<dim3(128, 2), 256, 0, stream>>>(CTX, WOT, bo, (float*)d_out);
}